// Round 15
// baseline (181.255 us; speedup 1.0000x reference)
//
#include <hip/hip_runtime.h>
#include <hip/hip_bf16.h>
#include <cstdint>

// Problem constants: B=2, T=2048, D_IN=D_OUT=1024, H=16, DH=64
#define SEQ_T 2048
#define DMODEL 1024
#define NHEAD 16
#define DHEAD 64

typedef __attribute__((ext_vector_type(8))) __bf16 bf16x8;
typedef __attribute__((ext_vector_type(4))) float floatx4;

static __device__ __forceinline__ uint16_t f2bf(float f) {
    union { float f; uint32_t u; } v; v.f = f;
    uint32_t r = v.u + 0x7FFFu + ((v.u >> 16) & 1u);   // RNE
    return (uint16_t)(r >> 16);
}

// -------- merged fp32->bf16 converts: z<4 weight transpose, z==4 x --------
// W_q (z==0) pre-scaled by 0.125*log2(e): QK^T emits s*C directly, so the
// attention softmax is a single raw v_exp_f32 (__builtin_amdgcn_exp2f).
__global__ void mha_cvt(const float* __restrict__ x, uint16_t* __restrict__ xb,
                        const float* __restrict__ W0, const float* __restrict__ W1,
                        const float* __restrict__ W2, const float* __restrict__ W3,
                        uint16_t* __restrict__ T0, uint16_t* __restrict__ T1,
                        uint16_t* __restrict__ T2, uint16_t* __restrict__ T3) {
    if (blockIdx.z == 4) {
        int base = (blockIdx.y * 16 + blockIdx.x) * 256 + threadIdx.x;
#pragma unroll
        for (int i = 0; i < 16; ++i) {
            int idx = base + i * 65536;
            float4 f = ((const float4*)x)[idx];
            union { uint16_t u[4]; uint64_t v; } o;
            o.u[0] = f2bf(f.x); o.u[1] = f2bf(f.y); o.u[2] = f2bf(f.z); o.u[3] = f2bf(f.w);
            ((uint64_t*)xb)[idx] = o.v;
        }
        return;
    }
    const float* W; uint16_t* Tt; float sc;
    switch (blockIdx.z) {
        case 0: W = W0; Tt = T0; sc = 0.125f * 1.44269504089f; break;
        case 1: W = W1; Tt = T1; sc = 1.f; break;
        case 2: W = W2; Tt = T2; sc = 1.f; break;
        default: W = W3; Tt = T3; sc = 1.f; break;
    }
    __shared__ float tile[64][65];
    const int c  = threadIdx.x & 63;
    const int r0 = threadIdx.x >> 6;
    const int R0 = blockIdx.y * 64, C0 = blockIdx.x * 64;
#pragma unroll
    for (int rr = 0; rr < 16; ++rr) {
        int r = r0 + rr * 4;
        tile[r][c] = W[(size_t)(R0 + r) * DMODEL + C0 + c];
    }
    __syncthreads();
#pragma unroll
    for (int rr = 0; rr < 16; ++rr) {
        int r = r0 + rr * 4;
        Tt[(size_t)(C0 + r) * DMODEL + R0 + c] = f2bf(tile[c][r] * sc);
    }
}

// ------ bf16 MFMA GEMM, 64M x 128N tile, BK=64, B^T input, swizzled ------
// (R10/R12-proven shape; qkv grid 1536 = 6 blocks/CU @ 24 KB dynamic LDS.)
// Swizzle: row r slot q' holds source sub-chunk q'^(r&7) -> 2-way-only.
// MODE 0: bf16 row-major out. MODE 1: Vt[(b*1024+col)*2048+t] via LDS
// transpose reusing staging smem.
template<int MODE>
__device__ __forceinline__ void gemm_bk64_body(
    const uint16_t* __restrict__ A, const uint16_t* __restrict__ Bt,
    uint16_t* __restrict__ outB) {
    const int K = DMODEL, N = DMODEL;
    extern __shared__ char smem[];                  // 24576 B dynamic
    uint16_t* As = (uint16_t*)smem;                 // [64][64]  8 KB
    uint16_t* Bs = (uint16_t*)(smem + 8192);        // [128][64] 16 KB
    const int tid  = threadIdx.x;
    const int wave = tid >> 6;
    const int lane = tid & 63;
    const int m0 = blockIdx.y * 64;
    const int n0 = blockIdx.x * 128;
    const int lr   = lane & 15;
    const int quad = lane >> 4;

    floatx4 acc[4][2];
#pragma unroll
    for (int i = 0; i < 4; ++i)
#pragma unroll
        for (int j = 0; j < 2; ++j) acc[i][j] = (floatx4)0.0f;

    for (int k0 = 0; k0 < K; k0 += 64) {
#pragma unroll
        for (int i = 0; i < 2; ++i) {               // A: 512 chunks (16B)
            int c = i * 256 + tid;
            int r = c >> 3, s = (c & 7) ^ (r & 7);
            const uint16_t* g = A + (size_t)(m0 + r) * K + k0 + s * 8;
            __builtin_amdgcn_global_load_lds((const __attribute__((address_space(1))) void*)g,
                                             (__attribute__((address_space(3))) void*)(As + (size_t)c * 8), 16, 0, 0);
        }
#pragma unroll
        for (int i = 0; i < 4; ++i) {               // B: 1024 chunks
            int c = i * 256 + tid;
            int r = c >> 3, s = (c & 7) ^ (r & 7);
            const uint16_t* g = Bt + (size_t)(n0 + r) * K + k0 + s * 8;
            __builtin_amdgcn_global_load_lds((const __attribute__((address_space(1))) void*)g,
                                             (__attribute__((address_space(3))) void*)(Bs + (size_t)c * 8), 16, 0, 0);
        }
        __syncthreads();
#pragma unroll
        for (int ks = 0; ks < 2; ++ks) {            // two 32-wide k-halves
            bf16x8 af[4], bfr[2];
#pragma unroll
            for (int mi = 0; mi < 4; ++mi) {
                int row = mi * 16 + lr;
                af[mi] = *(const bf16x8*)&As[row * 64 + (((ks * 4 + quad) ^ (row & 7)) << 3)];
            }
#pragma unroll
            for (int ni = 0; ni < 2; ++ni) {
                int row = wave * 32 + ni * 16 + lr;
                bfr[ni] = *(const bf16x8*)&Bs[row * 64 + (((ks * 4 + quad) ^ (row & 7)) << 3)];
            }
#pragma unroll
            for (int mi = 0; mi < 4; ++mi)
#pragma unroll
                for (int ni = 0; ni < 2; ++ni)
                    acc[mi][ni] = __builtin_amdgcn_mfma_f32_16x16x32_bf16(af[mi], bfr[ni], acc[mi][ni], 0, 0, 0);
        }
        __syncthreads();
    }
    if constexpr (MODE == 1) {
        uint16_t* Ct = (uint16_t*)smem;             // [128][72], 18.4 KB
        const int bb = m0 >> 11, t0 = m0 & 2047;
#pragma unroll
        for (int mi = 0; mi < 4; ++mi)
#pragma unroll
            for (int ni = 0; ni < 2; ++ni) {
                int cl = wave * 32 + ni * 16 + lr;
                int tl = mi * 16 + quad * 4;
                int tls = tl ^ ((cl & 3) << 4);     // 2-way-only bank pattern
                union { uint16_t u[4]; uint64_t v8; } pk;
#pragma unroll
                for (int r = 0; r < 4; ++r) pk.u[r] = f2bf(acc[mi][ni][r]);
                *(uint64_t*)&Ct[cl * 72 + tls] = pk.v8;
            }
        __syncthreads();
#pragma unroll
        for (int k = 0; k < 4; ++k) {
            int c = k * 256 + tid;                  // 1024 chunks of 16B
            int cl = c >> 3, off = (c & 7) * 8;
            int offs = off ^ ((cl & 3) << 4);
            uint4 v = *(const uint4*)&Ct[cl * 72 + offs];
            *(uint4*)&outB[((size_t)(bb * 1024 + n0 + cl)) * 2048 + t0 + off] = v;
        }
    } else {
#pragma unroll
        for (int mi = 0; mi < 4; ++mi)
#pragma unroll
            for (int ni = 0; ni < 2; ++ni) {
                int col = n0 + wave * 32 + ni * 16 + lr;
#pragma unroll
                for (int r = 0; r < 4; ++r) {
                    int row = m0 + mi * 16 + quad * 4 + r;
                    outB[(size_t)row * N + col] = f2bf(acc[mi][ni][r]);
                }
            }
    }
}

__global__ __launch_bounds__(256) void mha_gemm_qkv(
    const uint16_t* __restrict__ A,
    const uint16_t* __restrict__ Wq, const uint16_t* __restrict__ Wk, const uint16_t* __restrict__ Wv,
    uint16_t* __restrict__ Q, uint16_t* __restrict__ K, uint16_t* __restrict__ Vt) {
    switch (blockIdx.z) {
        case 0:  gemm_bk64_body<0>(A, Wq, Q);  break;
        case 1:  gemm_bk64_body<0>(A, Wk, K);  break;
        default: gemm_bk64_body<1>(A, Wv, Vt); break;
    }
}

// ---- out-projection GEMM: 64M x 64N, BK=64, 512 thr / 8 waves ----
// Grid (16,64) = 1024 blocks = 4 blocks/CU x 8 waves = 32 waves/CU (HW
// max). Doubling resident blocks halves exposed drain latency — this
// 8.6 GF GEMM is the most latency-bound kernel in the pipeline (est
// ~260 TF at 2 blocks/CU). Wave-tile 32x16, LDS 16 KB.
__global__ __launch_bounds__(512) void mha_gemm_out(
    const uint16_t* __restrict__ A, const uint16_t* __restrict__ Wot,
    float* __restrict__ out, const float* __restrict__ bias) {
    const int K = DMODEL, N = DMODEL;
    extern __shared__ char smem[];                  // 16384 B dynamic
    uint16_t* As = (uint16_t*)smem;                 // [64][64] 8 KB
    uint16_t* Bs = (uint16_t*)(smem + 8192);        // [64][64] 8 KB
    const int tid  = threadIdx.x;
    const int wave = tid >> 6;
    const int lane = tid & 63;
    const int m0 = blockIdx.y * 64;
    const int n0 = blockIdx.x * 64;
    const int lr   = lane & 15;
    const int quad = lane >> 4;
    const int wm = wave >> 2, wn = wave & 3;        // 2m x 4n wave grid

    floatx4 acc[2];
#pragma unroll
    for (int i = 0; i < 2; ++i) acc[i] = (floatx4)0.0f;

    for (int k0 = 0; k0 < K; k0 += 64) {
        {                                           // A: 512 chunks
            int c = tid;
            int r = c >> 3, s = (c & 7) ^ (r & 7);
            const uint16_t* g = A + (size_t)(m0 + r) * K + k0 + s * 8;
            __builtin_amdgcn_global_load_lds((const __attribute__((address_space(1))) void*)g,
                                             (__attribute__((address_space(3))) void*)(As + (size_t)c * 8), 16, 0, 0);
        }
        {                                           // B: 512 chunks
            int c = tid;
            int r = c >> 3, s = (c & 7) ^ (r & 7);
            const uint16_t* g = Wot + (size_t)(n0 + r) * K + k0 + s * 8;
            __builtin_amdgcn_global_load_lds((const __attribute__((address_space(1))) void*)g,
                                             (__attribute__((address_space(3))) void*)(Bs + (size_t)c * 8), 16, 0, 0);
        }
        __syncthreads();
#pragma unroll
        for (int ks = 0; ks < 2; ++ks) {
            bf16x8 af[2], bfr;
#pragma unroll
            for (int mi = 0; mi < 2; ++mi) {
                int row = wm * 32 + mi * 16 + lr;
                af[mi] = *(const bf16x8*)&As[row * 64 + (((ks * 4 + quad) ^ (row & 7)) << 3)];
            }
            {
                int row = wn * 16 + lr;
                bfr = *(const bf16x8*)&Bs[row * 64 + (((ks * 4 + quad) ^ (row & 7)) << 3)];
            }
#pragma unroll
            for (int mi = 0; mi < 2; ++mi)
                acc[mi] = __builtin_amdgcn_mfma_f32_16x16x32_bf16(af[mi], bfr, acc[mi], 0, 0, 0);
        }
        __syncthreads();
    }
    int col = n0 + wn * 16 + lr;
    float bv = bias[col];
#pragma unroll
    for (int mi = 0; mi < 2; ++mi)
#pragma unroll
        for (int r = 0; r < 4; ++r) {
            int row = m0 + wm * 32 + mi * 16 + quad * 4 + r;
            out[(size_t)row * N + col] = acc[mi][r] + bv;
        }
}

// ---------------- MFMA flash attention (causal, fixed-base softmax) -------
// R14 base (4 waves, 64-row paired q-tiles, XCD = h%8, async single-barrier
// dbuf, swizzled Pb, raw exp2, l via P·1 MFMA) + software-pipelined P path:
// S/exp/Pb-write for keys 0..31 (nt 0,1), then keys 32..63 (nt 2,3), then
// PV — the ks=0 Pb read's RAW-through-LDS latency hides behind half-B's
// MFMAs and exps instead of being fully exposed.
__global__ __launch_bounds__(256) void mha_attn_mfma(
    const uint16_t* __restrict__ Q, const uint16_t* __restrict__ K,
    const uint16_t* __restrict__ Vt, uint16_t* __restrict__ ctx) {
    __shared__ alignas(16) uint16_t Ks[2][64 * 64];   // 16 KB
    __shared__ alignas(16) uint16_t Vs[2][64 * 64];   // 16 KB
    __shared__ alignas(16) uint16_t Pb[64 * 64];      // 8 KB (swizzled)

    const int tid  = threadIdx.x;
    const int wave = tid >> 6;
    const int lane = tid & 63;
    const int lr   = lane & 15;
    const int quad = lane >> 4;
    const int h  = blockIdx.x;             // head fastest -> XCD locality
    const int p  = blockIdx.y;             // 0..15
    const int b  = blockIdx.z;
    const int jH = 31 - p, jL = p;         // 64-row q-tiles
    const int TH = jH + 1;
    const int TL = jL + 1;
    const int Ttot = TH + TL;              // 33 for every block

    const uint16_t* kbase[2];
    const uint16_t* vbase[2];
#pragma unroll
    for (int i = 0; i < 2; ++i) {
        int c = i * 256 + tid;             // chunk 0..511 (16B each)
        int row = c >> 3, cs = c & 7;
        int csk = cs ^ (row & 7);          // XOR source swizzle; dest linear
        kbase[i] = K  + ((size_t)(b * SEQ_T) + row) * DMODEL + h * DHEAD + csk * 8;
        vbase[i] = Vt + ((size_t)(b * 1024 + h * DHEAD + row)) * 2048 + csk * 8;
    }

    int wrow = jH * 64 + wave * 16;        // this wave's q-row base
    bf16x8 qf0, qf1;
    {
        const size_t qb = ((size_t)(b * SEQ_T) + wrow + lr) * DMODEL + h * DHEAD;
        qf0 = *(const bf16x8*)(Q + qb + quad * 8);
        qf1 = *(const bf16x8*)(Q + qb + 32 + quad * 8);
    }
    bf16x8 ones;
#pragma unroll
    for (int i = 0; i < 8; ++i) ones[i] = (__bf16)1.0f;

    floatx4 o[4];
#pragma unroll
    for (int nt = 0; nt < 4; ++nt) o[nt] = (floatx4)0.0f;
    floatx4 lacc = (floatx4)0.0f;          // l per row via MFMA ones-column

    auto stage = [&](int kv0, int buf) {
#pragma unroll
        for (int i = 0; i < 2; ++i) {
            const uint16_t* gk = kbase[i] + (size_t)kv0 * DMODEL;
            const uint16_t* gv = vbase[i] + kv0;
            uint16_t* lk = &Ks[buf][(i * 256 + wave * 64) * 8];
            uint16_t* lv = &Vs[buf][(i * 256 + wave * 64) * 8];
            __builtin_amdgcn_global_load_lds((const __attribute__((address_space(1))) void*)gk,
                                             (__attribute__((address_space(3))) void*)lk, 16, 0, 0);
            __builtin_amdgcn_global_load_lds((const __attribute__((address_space(1))) void*)gv,
                                             (__attribute__((address_space(3))) void*)lv, 16, 0, 0);
        }
    };
    auto epilogue = [&]() {
        float linv[4];
#pragma unroll
        for (int r = 0; r < 4; ++r) linv[r] = 1.f / lacc[r];
#pragma unroll
        for (int nt = 0; nt < 4; ++nt)
#pragma unroll
            for (int r = 0; r < 4; ++r) {
                size_t addr = ((size_t)(b * SEQ_T) + wrow + quad * 4 + r) * DMODEL + h * DHEAD + nt * 16 + lr;
                ctx[addr] = f2bf(o[nt][r] * linv[r]);
            }
    };

    stage(0, 0);
    __syncthreads();                       // tile 0 ready
    int cur = 0;

    for (int t = 0; t < Ttot; ++t) {
        if (t + 1 < Ttot) {
            int nkv0 = ((t + 1 < TH) ? (t + 1) : (t + 1 - TH)) * 64;
            stage(nkv0, cur ^ 1);          // in flight behind compute
        }
        const int kv0 = ((t < TH) ? t : (t - TH)) * 64;
        const bool diag = (kv0 + 63 > wrow);

        floatx4 s[4];
        // ---- half A: S, exp, Pb write for keys 0..31 (nt 0,1)
#pragma unroll
        for (int half = 0; half < 2; ++half) {
#pragma unroll
            for (int nt = half * 2; nt < half * 2 + 2; ++nt) {
                s[nt] = (floatx4)0.0f;
                int krow = nt * 16 + lr;
#pragma unroll
                for (int ks = 0; ks < 2; ++ks) {
                    bf16x8 kf = *(const bf16x8*)&Ks[cur][krow * 64 + (((ks * 4 + quad) ^ (lr & 7)) * 8)];
                    s[nt] = __builtin_amdgcn_mfma_f32_16x16x32_bf16(ks ? qf1 : qf0, kf, s[nt], 0, 0, 0);
                }
            }
            if (diag) {
#pragma unroll
                for (int nt = half * 2; nt < half * 2 + 2; ++nt) {
                    int kcol = kv0 + nt * 16 + lr;
#pragma unroll
                    for (int r = 0; r < 4; ++r) {
                        int qrow = wrow + quad * 4 + r;
                        if (kcol > qrow) s[nt][r] = -3e38f;
                    }
                }
            }
#pragma unroll
            for (int nt = half * 2; nt < half * 2 + 2; ++nt)
#pragma unroll
                for (int r = 0; r < 4; ++r) {
                    float pe = __builtin_amdgcn_exp2f(s[nt][r]);
                    int row = wave * 16 + quad * 4 + r;
                    int cc  = (nt * 2 + (lr >> 3)) ^ (row & 7);
                    Pb[row * 64 + cc * 8 + (lr & 7)] = (uint16_t)(__float_as_uint(pe) >> 16);
                }
        }
        // ---- PV: ks=0 reads keys 0..31 (written a half ago — latency
        // hidden behind half B's MFMAs/exps); l rides a ones-column MFMA
#pragma unroll
        for (int ks = 0; ks < 2; ++ks) {
            int prow = wave * 16 + lr;
            bf16x8 pfr = *(const bf16x8*)&Pb[prow * 64 + (((ks * 4 + quad) ^ (prow & 7)) * 8)];
            lacc = __builtin_amdgcn_mfma_f32_16x16x32_bf16(pfr, ones, lacc, 0, 0, 0);
#pragma unroll
            for (int nt = 0; nt < 4; ++nt) {
                int vrow = nt * 16 + lr;
                bf16x8 vf = *(const bf16x8*)&Vs[cur][vrow * 64 + (((ks * 4 + quad) ^ (lr & 7)) * 8)];
                o[nt] = __builtin_amdgcn_mfma_f32_16x16x32_bf16(pfr, vf, o[nt], 0, 0, 0);
            }
        }
        if (t == TH - 1) {
            epilogue();
            wrow = jL * 64 + wave * 16;
            const size_t qb = ((size_t)(b * SEQ_T) + wrow + lr) * DMODEL + h * DHEAD;
            qf0 = *(const bf16x8*)(Q + qb + quad * 8);
            qf1 = *(const bf16x8*)(Q + qb + 32 + quad * 8);
#pragma unroll
            for (int nt = 0; nt < 4; ++nt) o[nt] = (floatx4)0.0f;
            lacc = (floatx4)0.0f;
        }
        __syncthreads();
        cur ^= 1;
    }
    epilogue();                            // light q-tile output
}

extern "C" void kernel_launch(void* const* d_in, const int* in_sizes, int n_in,
                              void* d_out, int out_size, void* d_ws, size_t ws_size,
                              hipStream_t stream) {
    const float* x  = (const float*)d_in[0];
    const float* Wq = (const float*)d_in[1];
    const float* Wk = (const float*)d_in[2];
    const float* Wv = (const float*)d_in[3];
    const float* Wo = (const float*)d_in[4];
    const float* bo = (const float*)d_in[5];
    float* out = (float*)d_out;

    char* ws = (char*)d_ws;
    const size_t SZ_X = (size_t)4096 * DMODEL * 2;   // 8 MB
    const size_t SZ_W = (size_t)DMODEL * DMODEL * 2; // 2 MB
    size_t off = 0;
    uint16_t* xb  = (uint16_t*)(ws + off); off += SZ_X;
    uint16_t* wqt = (uint16_t*)(ws + off); off += SZ_W;
    uint16_t* wkt = (uint16_t*)(ws + off); off += SZ_W;
    uint16_t* wvt = (uint16_t*)(ws + off); off += SZ_W;
    uint16_t* wot = (uint16_t*)(ws + off); off += SZ_W;
    uint16_t* Qb  = (uint16_t*)(ws + off); off += SZ_X;
    uint16_t* Kb  = (uint16_t*)(ws + off); off += SZ_X;
    uint16_t* Vtb = (uint16_t*)(ws + off); off += SZ_X;  // per-head transposed V
    uint16_t* Cb  = (uint16_t*)(ws + off); off += SZ_X;
    (void)ws_size; (void)in_sizes; (void)n_in; (void)out_size;

    mha_cvt<<<dim3(16, 16, 5), 256, 0, stream>>>(x, xb, Wq, Wk, Wv, Wo, wqt, wkt, wvt, wot);
    mha_gemm_qkv<<<dim3(8, 64, 3), 256, 24576, stream>>>(xb, wqt, wkt, wvt, Qb, Kb, Vtb);
    mha_attn_mfma<<<dim3(NHEAD, 16, 2), 256, 0, stream>>>(Qb, Kb, Vtb, Cb);
    mha_gemm_out<<<dim3(16, 64), 512, 16384, stream>>>(Cb, wot, out, bo);
}

// Round 16
// 174.987 us; speedup vs baseline: 1.0358x; 1.0358x over previous
//
#include <hip/hip_runtime.h>
#include <hip/hip_bf16.h>
#include <cstdint>

// Problem constants: B=2, T=2048, D_IN=D_OUT=1024, H=16, DH=64
#define SEQ_T 2048
#define DMODEL 1024
#define NHEAD 16
#define DHEAD 64

typedef __attribute__((ext_vector_type(8))) __bf16 bf16x8;
typedef __attribute__((ext_vector_type(4))) float floatx4;

static __device__ __forceinline__ uint16_t f2bf(float f) {
    union { float f; uint32_t u; } v; v.f = f;
    uint32_t r = v.u + 0x7FFFu + ((v.u >> 16) & 1u);   // RNE
    return (uint16_t)(r >> 16);
}

// -------- merged fp32->bf16 converts: z<4 weight transpose, z==4 x --------
// W_q (z==0) pre-scaled by 0.125*log2(e): QK^T emits s*C directly, so the
// attention softmax is a single raw v_exp_f32 (__builtin_amdgcn_exp2f).
__global__ void mha_cvt(const float* __restrict__ x, uint16_t* __restrict__ xb,
                        const float* __restrict__ W0, const float* __restrict__ W1,
                        const float* __restrict__ W2, const float* __restrict__ W3,
                        uint16_t* __restrict__ T0, uint16_t* __restrict__ T1,
                        uint16_t* __restrict__ T2, uint16_t* __restrict__ T3) {
    if (blockIdx.z == 4) {
        int base = (blockIdx.y * 16 + blockIdx.x) * 256 + threadIdx.x;
#pragma unroll
        for (int i = 0; i < 16; ++i) {
            int idx = base + i * 65536;
            float4 f = ((const float4*)x)[idx];
            union { uint16_t u[4]; uint64_t v; } o;
            o.u[0] = f2bf(f.x); o.u[1] = f2bf(f.y); o.u[2] = f2bf(f.z); o.u[3] = f2bf(f.w);
            ((uint64_t*)xb)[idx] = o.v;
        }
        return;
    }
    const float* W; uint16_t* Tt; float sc;
    switch (blockIdx.z) {
        case 0: W = W0; Tt = T0; sc = 0.125f * 1.44269504089f; break;
        case 1: W = W1; Tt = T1; sc = 1.f; break;
        case 2: W = W2; Tt = T2; sc = 1.f; break;
        default: W = W3; Tt = T3; sc = 1.f; break;
    }
    __shared__ float tile[64][65];
    const int c  = threadIdx.x & 63;
    const int r0 = threadIdx.x >> 6;
    const int R0 = blockIdx.y * 64, C0 = blockIdx.x * 64;
#pragma unroll
    for (int rr = 0; rr < 16; ++rr) {
        int r = r0 + rr * 4;
        tile[r][c] = W[(size_t)(R0 + r) * DMODEL + C0 + c];
    }
    __syncthreads();
#pragma unroll
    for (int rr = 0; rr < 16; ++rr) {
        int r = r0 + rr * 4;
        Tt[(size_t)(C0 + r) * DMODEL + R0 + c] = f2bf(tile[c][r] * sc);
    }
}

// ------ bf16 MFMA GEMM, 64M x 128N tile, BK=64, B^T input, swizzled ------
// (R10/R12-proven shape; qkv grid 1536 = 6 blocks/CU @ 24 KB dynamic LDS.)
// Swizzle: row r slot q' holds source sub-chunk q'^(r&7) -> 2-way-only.
// MODE 0: bf16 row-major out. MODE 1: Vt[(b*1024+col)*2048+t] via LDS
// transpose reusing staging smem.
template<int MODE>
__device__ __forceinline__ void gemm_bk64_body(
    const uint16_t* __restrict__ A, const uint16_t* __restrict__ Bt,
    uint16_t* __restrict__ outB) {
    const int K = DMODEL, N = DMODEL;
    extern __shared__ char smem[];                  // 24576 B dynamic
    uint16_t* As = (uint16_t*)smem;                 // [64][64]  8 KB
    uint16_t* Bs = (uint16_t*)(smem + 8192);        // [128][64] 16 KB
    const int tid  = threadIdx.x;
    const int wave = tid >> 6;
    const int lane = tid & 63;
    const int m0 = blockIdx.y * 64;
    const int n0 = blockIdx.x * 128;
    const int lr   = lane & 15;
    const int quad = lane >> 4;

    floatx4 acc[4][2];
#pragma unroll
    for (int i = 0; i < 4; ++i)
#pragma unroll
        for (int j = 0; j < 2; ++j) acc[i][j] = (floatx4)0.0f;

    for (int k0 = 0; k0 < K; k0 += 64) {
#pragma unroll
        for (int i = 0; i < 2; ++i) {               // A: 512 chunks (16B)
            int c = i * 256 + tid;
            int r = c >> 3, s = (c & 7) ^ (r & 7);
            const uint16_t* g = A + (size_t)(m0 + r) * K + k0 + s * 8;
            __builtin_amdgcn_global_load_lds((const __attribute__((address_space(1))) void*)g,
                                             (__attribute__((address_space(3))) void*)(As + (size_t)c * 8), 16, 0, 0);
        }
#pragma unroll
        for (int i = 0; i < 4; ++i) {               // B: 1024 chunks
            int c = i * 256 + tid;
            int r = c >> 3, s = (c & 7) ^ (r & 7);
            const uint16_t* g = Bt + (size_t)(n0 + r) * K + k0 + s * 8;
            __builtin_amdgcn_global_load_lds((const __attribute__((address_space(1))) void*)g,
                                             (__attribute__((address_space(3))) void*)(Bs + (size_t)c * 8), 16, 0, 0);
        }
        __syncthreads();
#pragma unroll
        for (int ks = 0; ks < 2; ++ks) {            // two 32-wide k-halves
            bf16x8 af[4], bfr[2];
#pragma unroll
            for (int mi = 0; mi < 4; ++mi) {
                int row = mi * 16 + lr;
                af[mi] = *(const bf16x8*)&As[row * 64 + (((ks * 4 + quad) ^ (row & 7)) << 3)];
            }
#pragma unroll
            for (int ni = 0; ni < 2; ++ni) {
                int row = wave * 32 + ni * 16 + lr;
                bfr[ni] = *(const bf16x8*)&Bs[row * 64 + (((ks * 4 + quad) ^ (row & 7)) << 3)];
            }
#pragma unroll
            for (int mi = 0; mi < 4; ++mi)
#pragma unroll
                for (int ni = 0; ni < 2; ++ni)
                    acc[mi][ni] = __builtin_amdgcn_mfma_f32_16x16x32_bf16(af[mi], bfr[ni], acc[mi][ni], 0, 0, 0);
        }
        __syncthreads();
    }
    if constexpr (MODE == 1) {
        uint16_t* Ct = (uint16_t*)smem;             // [128][72], 18.4 KB
        const int bb = m0 >> 11, t0 = m0 & 2047;
#pragma unroll
        for (int mi = 0; mi < 4; ++mi)
#pragma unroll
            for (int ni = 0; ni < 2; ++ni) {
                int cl = wave * 32 + ni * 16 + lr;
                int tl = mi * 16 + quad * 4;
                int tls = tl ^ ((cl & 3) << 4);     // 2-way-only bank pattern
                union { uint16_t u[4]; uint64_t v8; } pk;
#pragma unroll
                for (int r = 0; r < 4; ++r) pk.u[r] = f2bf(acc[mi][ni][r]);
                *(uint64_t*)&Ct[cl * 72 + tls] = pk.v8;
            }
        __syncthreads();
#pragma unroll
        for (int k = 0; k < 4; ++k) {
            int c = k * 256 + tid;                  // 1024 chunks of 16B
            int cl = c >> 3, off = (c & 7) * 8;
            int offs = off ^ ((cl & 3) << 4);
            uint4 v = *(const uint4*)&Ct[cl * 72 + offs];
            *(uint4*)&outB[((size_t)(bb * 1024 + n0 + cl)) * 2048 + t0 + off] = v;
        }
    } else {
#pragma unroll
        for (int mi = 0; mi < 4; ++mi)
#pragma unroll
            for (int ni = 0; ni < 2; ++ni) {
                int col = n0 + wave * 32 + ni * 16 + lr;
#pragma unroll
                for (int r = 0; r < 4; ++r) {
                    int row = m0 + mi * 16 + quad * 4 + r;
                    outB[(size_t)row * N + col] = f2bf(acc[mi][ni][r]);
                }
            }
    }
}

__global__ __launch_bounds__(256) void mha_gemm_qkv(
    const uint16_t* __restrict__ A,
    const uint16_t* __restrict__ Wq, const uint16_t* __restrict__ Wk, const uint16_t* __restrict__ Wv,
    uint16_t* __restrict__ Q, uint16_t* __restrict__ K, uint16_t* __restrict__ Vt) {
    switch (blockIdx.z) {
        case 0:  gemm_bk64_body<0>(A, Wq, Q);  break;
        case 1:  gemm_bk64_body<0>(A, Wk, K);  break;
        default: gemm_bk64_body<1>(A, Wv, Vt); break;
    }
}

// ---- out-projection GEMM: 64M x 128N, BK=64, 512 thr / 8 waves ----
// (R14-best config: wave-tile 32x32, grid (8,64) = 2 blocks/CU x 8 waves
// = 16 waves/CU. R15's 64x64 retile regressed ~3.6 µs — reverted.)
__global__ __launch_bounds__(512) void mha_gemm_out(
    const uint16_t* __restrict__ A, const uint16_t* __restrict__ Wot,
    float* __restrict__ out, const float* __restrict__ bias) {
    const int K = DMODEL, N = DMODEL;
    extern __shared__ char smem[];                  // 24576 B dynamic
    uint16_t* As = (uint16_t*)smem;                 // [64][64]  8 KB
    uint16_t* Bs = (uint16_t*)(smem + 8192);        // [128][64] 16 KB
    const int tid  = threadIdx.x;
    const int wave = tid >> 6;
    const int lane = tid & 63;
    const int m0 = blockIdx.y * 64;
    const int n0 = blockIdx.x * 128;
    const int lr   = lane & 15;
    const int quad = lane >> 4;
    const int wm = wave >> 2, wn = wave & 3;        // 2m x 4n wave grid

    floatx4 acc[2][2];
#pragma unroll
    for (int i = 0; i < 2; ++i)
#pragma unroll
        for (int j = 0; j < 2; ++j) acc[i][j] = (floatx4)0.0f;

    for (int k0 = 0; k0 < K; k0 += 64) {
        {                                           // A: 512 chunks
            int c = tid;
            int r = c >> 3, s = (c & 7) ^ (r & 7);
            const uint16_t* g = A + (size_t)(m0 + r) * K + k0 + s * 8;
            __builtin_amdgcn_global_load_lds((const __attribute__((address_space(1))) void*)g,
                                             (__attribute__((address_space(3))) void*)(As + (size_t)c * 8), 16, 0, 0);
        }
#pragma unroll
        for (int i = 0; i < 2; ++i) {               // B: 1024 chunks
            int c = i * 512 + tid;
            int r = c >> 3, s = (c & 7) ^ (r & 7);
            const uint16_t* g = Wot + (size_t)(n0 + r) * K + k0 + s * 8;
            __builtin_amdgcn_global_load_lds((const __attribute__((address_space(1))) void*)g,
                                             (__attribute__((address_space(3))) void*)(Bs + (size_t)c * 8), 16, 0, 0);
        }
        __syncthreads();
#pragma unroll
        for (int ks = 0; ks < 2; ++ks) {
            bf16x8 af[2], bfr[2];
#pragma unroll
            for (int mi = 0; mi < 2; ++mi) {
                int row = wm * 32 + mi * 16 + lr;
                af[mi] = *(const bf16x8*)&As[row * 64 + (((ks * 4 + quad) ^ (row & 7)) << 3)];
            }
#pragma unroll
            for (int ni = 0; ni < 2; ++ni) {
                int row = wn * 32 + ni * 16 + lr;
                bfr[ni] = *(const bf16x8*)&Bs[row * 64 + (((ks * 4 + quad) ^ (row & 7)) << 3)];
            }
#pragma unroll
            for (int mi = 0; mi < 2; ++mi)
#pragma unroll
                for (int ni = 0; ni < 2; ++ni)
                    acc[mi][ni] = __builtin_amdgcn_mfma_f32_16x16x32_bf16(af[mi], bfr[ni], acc[mi][ni], 0, 0, 0);
        }
        __syncthreads();
    }
#pragma unroll
    for (int mi = 0; mi < 2; ++mi)
#pragma unroll
        for (int ni = 0; ni < 2; ++ni) {
            int col = n0 + wn * 32 + ni * 16 + lr;
            float bv = bias[col];
#pragma unroll
            for (int r = 0; r < 4; ++r) {
                int row = m0 + wm * 32 + mi * 16 + quad * 4 + r;
                out[(size_t)row * N + col] = acc[mi][ni][r] + bv;
            }
        }
}

// ---------------- MFMA flash attention (causal, fixed-base softmax) -------
// R14 base (4 waves, 64-row paired q-tiles, XCD = h%8, swizzled Pb, raw
// exp2, l via P·1 MFMA) + NEW: depth-2 async prefetch over a 3-buffer
// rotation with manual s_waitcnt vmcnt(4) + raw s_barrier (m139 pattern).
// __syncthreads' vmcnt(0) drain exposed ~400+ cyc of load latency every
// iteration (measured ~840 cyc/iter vs ~350 cyc compute); waiting only
// the OLDEST 4 loads (tile t+1, issued a full iteration ago) lets the
// newest stage fly across the barrier. Correctness: per-wave vmcnt(4) +
// barrier => all waves' t+1 loads landed before anyone reads that buffer;
// buffer reuse distance is 3 iters; Pb is wave-private.
__global__ __launch_bounds__(256) void mha_attn_mfma(
    const uint16_t* __restrict__ Q, const uint16_t* __restrict__ K,
    const uint16_t* __restrict__ Vt, uint16_t* __restrict__ ctx) {
    __shared__ alignas(16) uint16_t Ks[3][64 * 64];   // 24 KB
    __shared__ alignas(16) uint16_t Vs[3][64 * 64];   // 24 KB
    __shared__ alignas(16) uint16_t Pb[64 * 64];      // 8 KB (swizzled)

    const int tid  = threadIdx.x;
    const int wave = tid >> 6;
    const int lane = tid & 63;
    const int lr   = lane & 15;
    const int quad = lane >> 4;
    const int h  = blockIdx.x;             // head fastest -> XCD locality
    const int p  = blockIdx.y;             // 0..15
    const int b  = blockIdx.z;
    const int jH = 31 - p, jL = p;         // 64-row q-tiles
    const int TH = jH + 1;
    const int TL = jL + 1;
    const int Ttot = TH + TL;              // 33 for every block

    const uint16_t* kbase[2];
    const uint16_t* vbase[2];
#pragma unroll
    for (int i = 0; i < 2; ++i) {
        int c = i * 256 + tid;             // chunk 0..511 (16B each)
        int row = c >> 3, cs = c & 7;
        int csk = cs ^ (row & 7);          // XOR source swizzle; dest linear
        kbase[i] = K  + ((size_t)(b * SEQ_T) + row) * DMODEL + h * DHEAD + csk * 8;
        vbase[i] = Vt + ((size_t)(b * 1024 + h * DHEAD + row)) * 2048 + csk * 8;
    }

    int wrow = jH * 64 + wave * 16;        // this wave's q-row base
    bf16x8 qf0, qf1;
    {
        const size_t qb = ((size_t)(b * SEQ_T) + wrow + lr) * DMODEL + h * DHEAD;
        qf0 = *(const bf16x8*)(Q + qb + quad * 8);
        qf1 = *(const bf16x8*)(Q + qb + 32 + quad * 8);
    }
    bf16x8 ones;
#pragma unroll
    for (int i = 0; i < 8; ++i) ones[i] = (__bf16)1.0f;

    floatx4 o[4];
#pragma unroll
    for (int nt = 0; nt < 4; ++nt) o[nt] = (floatx4)0.0f;
    floatx4 lacc = (floatx4)0.0f;          // l per row via MFMA ones-column

    auto kvof = [&](int t) { return ((t < TH) ? t : (t - TH)) * 64; };
    // issues exactly 4 global_load_lds per thread
    auto stage = [&](int kv0, int buf) {
#pragma unroll
        for (int i = 0; i < 2; ++i) {
            const uint16_t* gk = kbase[i] + (size_t)kv0 * DMODEL;
            const uint16_t* gv = vbase[i] + kv0;
            uint16_t* lk = &Ks[buf][(i * 256 + wave * 64) * 8];
            uint16_t* lv = &Vs[buf][(i * 256 + wave * 64) * 8];
            __builtin_amdgcn_global_load_lds((const __attribute__((address_space(1))) void*)gk,
                                             (__attribute__((address_space(3))) void*)lk, 16, 0, 0);
            __builtin_amdgcn_global_load_lds((const __attribute__((address_space(1))) void*)gv,
                                             (__attribute__((address_space(3))) void*)lv, 16, 0, 0);
        }
    };
    auto epilogue = [&]() {
        float linv[4];
#pragma unroll
        for (int r = 0; r < 4; ++r) linv[r] = 1.f / lacc[r];
#pragma unroll
        for (int nt = 0; nt < 4; ++nt)
#pragma unroll
            for (int r = 0; r < 4; ++r) {
                size_t addr = ((size_t)(b * SEQ_T) + wrow + quad * 4 + r) * DMODEL + h * DHEAD + nt * 16 + lr;
                ctx[addr] = f2bf(o[nt][r] * linv[r]);
            }
    };

    stage(kvof(0), 0);
    stage(kvof(1), 1);                     // 8 loads in flight
    // wait oldest 4 (tile 0) only; tile 1 keeps flying across the barrier
    __builtin_amdgcn_s_waitcnt(0x0F74);    // vmcnt(4), lgkm/exp no-wait
    __builtin_amdgcn_s_barrier();

    for (int t = 0; t < Ttot; ++t) {
        if (t + 2 < Ttot) stage(kvof(t + 2), (t + 2) % 3);
        const int cur = t % 3;
        const int kv0 = kvof(t);

        floatx4 s[4];
#pragma unroll
        for (int nt = 0; nt < 4; ++nt) {
            s[nt] = (floatx4)0.0f;
            int krow = nt * 16 + lr;
#pragma unroll
            for (int ks = 0; ks < 2; ++ks) {
                bf16x8 kf = *(const bf16x8*)&Ks[cur][krow * 64 + (((ks * 4 + quad) ^ (lr & 7)) * 8)];
                s[nt] = __builtin_amdgcn_mfma_f32_16x16x32_bf16(ks ? qf1 : qf0, kf, s[nt], 0, 0, 0);
            }
        }
        if (kv0 + 63 > wrow) {
#pragma unroll
            for (int nt = 0; nt < 4; ++nt) {
                int kcol = kv0 + nt * 16 + lr;
#pragma unroll
                for (int r = 0; r < 4; ++r) {
                    int qrow = wrow + quad * 4 + r;
                    if (kcol > qrow) s[nt][r] = -3e38f;
                }
            }
        }
        // p = exp2(s) via raw v_exp_f32 (scale folded into W_q); truncate
        // to bf16 into swizzled wave-private Pb; l rides the P·1 MFMA.
#pragma unroll
        for (int nt = 0; nt < 4; ++nt)
#pragma unroll
            for (int r = 0; r < 4; ++r) {
                float pe = __builtin_amdgcn_exp2f(s[nt][r]);
                int row = wave * 16 + quad * 4 + r;
                int cc  = (nt * 2 + (lr >> 3)) ^ (row & 7);
                Pb[row * 64 + cc * 8 + (lr & 7)] = (uint16_t)(__float_as_uint(pe) >> 16);
            }
#pragma unroll
        for (int ks = 0; ks < 2; ++ks) {
            int prow = wave * 16 + lr;
            bf16x8 pfr = *(const bf16x8*)&Pb[prow * 64 + (((ks * 4 + quad) ^ (prow & 7)) * 8)];
            lacc = __builtin_amdgcn_mfma_f32_16x16x32_bf16(pfr, ones, lacc, 0, 0, 0);
#pragma unroll
            for (int nt = 0; nt < 4; ++nt) {
                int vrow = nt * 16 + lr;
                bf16x8 vf = *(const bf16x8*)&Vs[cur][vrow * 64 + (((ks * 4 + quad) ^ (lr & 7)) * 8)];
                o[nt] = __builtin_amdgcn_mfma_f32_16x16x32_bf16(pfr, vf, o[nt], 0, 0, 0);
            }
        }
        if (t == TH - 1) {
            epilogue();
            wrow = jL * 64 + wave * 16;
            const size_t qb = ((size_t)(b * SEQ_T) + wrow + lr) * DMODEL + h * DHEAD;
            qf0 = *(const bf16x8*)(Q + qb + quad * 8);
            qf1 = *(const bf16x8*)(Q + qb + 32 + quad * 8);
#pragma unroll
            for (int nt = 0; nt < 4; ++nt) o[nt] = (floatx4)0.0f;
            lacc = (floatx4)0.0f;
        }
        // end-of-iter sync: drain only the oldest outstanding stage (tile
        // t+1); the stage issued THIS iteration (t+2) crosses the barrier
        // still in flight. Last tile needs no barrier at all.
        if (t + 2 < Ttot) {
            __builtin_amdgcn_s_waitcnt(0x0F74);    // vmcnt(4)
            __builtin_amdgcn_s_barrier();
        } else if (t + 1 < Ttot) {
            __builtin_amdgcn_s_waitcnt(0x0F70);    // vmcnt(0): final drain
            __builtin_amdgcn_s_barrier();
        }
    }
    epilogue();                            // light q-tile output
}

extern "C" void kernel_launch(void* const* d_in, const int* in_sizes, int n_in,
                              void* d_out, int out_size, void* d_ws, size_t ws_size,
                              hipStream_t stream) {
    const float* x  = (const float*)d_in[0];
    const float* Wq = (const float*)d_in[1];
    const float* Wk = (const float*)d_in[2];
    const float* Wv = (const float*)d_in[3];
    const float* Wo = (const float*)d_in[4];
    const float* bo = (const float*)d_in[5];
    float* out = (float*)d_out;

    char* ws = (char*)d_ws;
    const size_t SZ_X = (size_t)4096 * DMODEL * 2;   // 8 MB
    const size_t SZ_W = (size_t)DMODEL * DMODEL * 2; // 2 MB
    size_t off = 0;
    uint16_t* xb  = (uint16_t*)(ws + off); off += SZ_X;
    uint16_t* wqt = (uint16_t*)(ws + off); off += SZ_W;
    uint16_t* wkt = (uint16_t*)(ws + off); off += SZ_W;
    uint16_t* wvt = (uint16_t*)(ws + off); off += SZ_W;
    uint16_t* wot = (uint16_t*)(ws + off); off += SZ_W;
    uint16_t* Qb  = (uint16_t*)(ws + off); off += SZ_X;
    uint16_t* Kb  = (uint16_t*)(ws + off); off += SZ_X;
    uint16_t* Vtb = (uint16_t*)(ws + off); off += SZ_X;  // per-head transposed V
    uint16_t* Cb  = (uint16_t*)(ws + off); off += SZ_X;
    (void)ws_size; (void)in_sizes; (void)n_in; (void)out_size;

    mha_cvt<<<dim3(16, 16, 5), 256, 0, stream>>>(x, xb, Wq, Wk, Wv, Wo, wqt, wkt, wvt, wot);
    mha_gemm_qkv<<<dim3(8, 64, 3), 256, 24576, stream>>>(xb, wqt, wkt, wvt, Qb, Kb, Vtb);
    mha_attn_mfma<<<dim3(NHEAD, 16, 2), 256, 0, stream>>>(Qb, Kb, Vtb, Cb);
    mha_gemm_out<<<dim3(8, 64), 512, 24576, stream>>>(Cb, wot, out, bo);
}